// Round 3
// baseline (538.196 us; speedup 1.0000x reference)
//
#include <hip/hip_runtime.h>
#include <hip/hip_bf16.h>

typedef __bf16 bf16;
typedef __bf16 bf16x4 __attribute__((ext_vector_type(4)));
typedef __bf16 bf16x8 __attribute__((ext_vector_type(8)));
typedef float  f32x4  __attribute__((ext_vector_type(4)));

#define AS1 __attribute__((address_space(1)))
#define AS3 __attribute__((address_space(3)))

__device__ __forceinline__ void gld_lds16(const void* g, void* l) {
    // async global->LDS, 16B per lane; LDS dest = wave-uniform base + lane*16
    __builtin_amdgcn_global_load_lds((AS1 void*)g, (AS3 void*)l, 16, 0, 0);
}

// ---------------------------------------------------------------------------
// fp32 -> bf16 bulk convert, float4-vectorized grid-stride
// ---------------------------------------------------------------------------
__global__ void cvt_kernel(const float* __restrict__ in, bf16* __restrict__ out,
                           int n4) {
    for (long i = (long)blockIdx.x * blockDim.x + threadIdx.x; i < n4;
         i += (long)gridDim.x * blockDim.x) {
        f32x4 v = ((const f32x4*)in)[i];
        bf16x4 h;
#pragma unroll
        for (int e = 0; e < 4; ++e) h[e] = (bf16)v[e];
        ((bf16x4*)out)[i] = h;
    }
}

// ---------------------------------------------------------------------------
// bias[h][i][j] = table[rel_index[i*64+j]][h]   (all fp32)
// ---------------------------------------------------------------------------
__global__ void bias_kernel(const int* __restrict__ rel_index,
                            const float* __restrict__ table,
                            float* __restrict__ bias) {
    int idx = blockIdx.x * 256 + threadIdx.x;   // 0..65535 = h*4096 + rc
    int rc = idx & 4095;
    int h  = idx >> 12;
    bias[idx] = table[rel_index[rc] * 16 + h];
}

// ---------------------------------------------------------------------------
// Shared 8-phase GEMM machinery.  LDS tiles [slot][kk][256 rows][32 k] bf16
// (64-B rows).  Chunk swizzle key = (row>>2)&3: the colliding lane set of a
// fragment ds_read_b128 is {r16, r16+4, r16+8, r16+12} (64-B row stride ->
// rows 4 apart alias the same 4-bank group); key must distinguish r16>>2.
// Staged via pre-swizzled global source (both-sides involution, rule #21).
//
// Fragment-register double-buffer (m201 mechanism): phase p's top issues the
// ds_reads for phase p+1 into the alternate reg set; the MFMA waits with
// COUNTED lgkmcnt (4 odd phases / 8 even) so only the previous phase's
// (already completed) reads gate it -> LDS burst overlaps MFMA.
// vmcnt ring: counted waits vmcnt(6) at ph3/ph5/ph7, vmcnt(4) at ph8;
// every staged region retires exactly one wait before its first (prefetch)
// read, with cross-wave visibility via the barrier that follows the wait.
// ---------------------------------------------------------------------------
#define STAGE(GBASE, LBASE, SK0)                                          \
    { _Pragma("unroll")                                                   \
      for (int c_ = 0; c_ < 2; ++c_)                                      \
          gld_lds16((GBASE) + c_ * 16 * 512 + (SK0),                      \
                    (LBASE) + (w * 2 + c_) * 512); }

#define FRAG_A(DST, S, KK, IH)                                              \
  { const bf16* ap_ = sA + ((S)*2+(KK))*8192 + (wm128+(IH)*64+r16)*32 + cq8;\
    _Pragma("unroll")                                                       \
    for (int ii_ = 0; ii_ < 4; ++ii_)                                       \
        DST[ii_] = *(const bf16x8*)(ap_ + ii_*512); }

#define FRAG_B(DST, S, KK)                                                  \
  { const bf16* bp_ = sB + ((S)*2+(KK))*8192 + (wn64+r16)*32 + cq8;         \
    _Pragma("unroll")                                                       \
    for (int jj_ = 0; jj_ < 4; ++jj_)                                       \
        DST[jj_] = *(const bf16x8*)(bp_ + jj_*512); }

// One phase: prefetch next phase's fragments | stage | barrier |
// counted lgkmcnt | MFMA (setprio) | [counted vmcnt] | barrier.
#define PH(PFAD, PFS, PFKK, PFIH, PFB, PFBD, GB, LB, SK0, LGK, UAV, UBV,    \
           UIH, VMA)                                                        \
  { FRAG_A(PFAD, PFS, PFKK, PFIH);                                          \
    if (PFB) FRAG_B(PFBD, PFS, PFKK);                                       \
    STAGE(GB, LB, SK0);                                                     \
    __builtin_amdgcn_sched_barrier(0);                                      \
    __builtin_amdgcn_s_barrier();                                           \
    asm volatile("s_waitcnt lgkmcnt(" #LGK ")");                            \
    __builtin_amdgcn_sched_barrier(0);                                      \
    __builtin_amdgcn_s_setprio(1);                                          \
    _Pragma("unroll")                                                       \
    for (int ii_ = 0; ii_ < 4; ++ii_)                                       \
      _Pragma("unroll")                                                     \
      for (int jj_ = 0; jj_ < 4; ++jj_)                                     \
        acc[(UIH)*4+ii_][jj_] = __builtin_amdgcn_mfma_f32_16x16x32_bf16(    \
            UAV[ii_], UBV[jj_], acc[(UIH)*4+ii_][jj_], 0, 0, 0);            \
    __builtin_amdgcn_s_setprio(0);                                          \
    asm volatile(VMA);                                                      \
    __builtin_amdgcn_sched_barrier(0);                                      \
    __builtin_amdgcn_s_barrier(); }

#define GEMM_PREAMBLE                                                       \
    __shared__ __attribute__((aligned(16))) char smemraw[131072];           \
    bf16* sA = (bf16*)smemraw;                                              \
    bf16* sB = sA + 32768;                                                  \
    const int t     = threadIdx.x;                                          \
    const int w     = t >> 6;                                               \
    const int lane  = t & 63;                                               \
    const int q     = lane >> 4;                                            \
    const int r16   = lane & 15;                                            \
    const int wm128 = (w >> 2) * 128;                                       \
    const int wn64  = (w & 3) * 64;                                         \
    const int sc8   = (((lane & 3) ^ ((lane >> 4) & 3)) << 3);              \
    const int cq8   = ((q ^ ((r16 >> 2) & 3)) << 3);

#define GEMM_MAIN(ABASE, BBASE)                                             \
    const bf16* Ast = (ABASE) + (bM + w * 32 + (lane >> 2)) * 512 + sc8;    \
    const bf16* Bst = (BBASE) + (bN + w * 32 + (lane >> 2)) * 512 + sc8;    \
    f32x4 acc[8][4];                                                        \
    _Pragma("unroll")                                                       \
    for (int i = 0; i < 8; ++i)                                             \
        _Pragma("unroll")                                                   \
        for (int j = 0; j < 4; ++j) acc[i][j] = f32x4{0.f, 0.f, 0.f, 0.f};  \
    bf16x8 avA[4], avB[4], bvA[4], bvB[4];                                  \
    STAGE(Ast, sA + 0,     0);                                              \
    STAGE(Bst, sB + 0,     0);                                              \
    STAGE(Ast, sA + 8192,  32);                                             \
    STAGE(Bst, sB + 8192,  32);                                             \
    STAGE(Ast, sA + 16384, 64);                                             \
    STAGE(Bst, sB + 16384, 64);                                             \
    asm volatile("s_waitcnt vmcnt(4)");                                     \
    __builtin_amdgcn_sched_barrier(0);                                      \
    __builtin_amdgcn_s_barrier();                                           \
    FRAG_A(avA, 0, 0, 0);                                                   \
    FRAG_B(bvA, 0, 0);                                                      \
    for (int i = 0; i < 4; ++i) {                                           \
        const int t1 = 2 * i + 1;                                           \
        const int t2 = (2 * i + 2 < 8) ? 2 * i + 2 : 7;                     \
        const int t3 = (2 * i + 3 < 8) ? 2 * i + 3 : 7;                     \
        PH(avB,0,0,1, 0,bvB, Ast, sA+24576, t1*64+32, 4, avA,bvA,0, "")     \
        PH(avA,0,1,1, 1,bvB, Bst, sB+24576, t1*64+32, 8, avB,bvA,1, "")     \
        PH(avB,0,1,0, 0,bvA, Ast, sA+0,     t2*64,    4, avA,bvB,1,         \
           "s_waitcnt vmcnt(6)")                                            \
        PH(avA,1,0,0, 1,bvA, Bst, sB+0,     t2*64,    8, avB,bvB,0, "")     \
        PH(avB,1,0,1, 0,bvB, Ast, sA+8192,  t2*64+32, 4, avA,bvA,0,         \
           "s_waitcnt vmcnt(6)")                                            \
        PH(avA,1,1,1, 1,bvB, Bst, sB+8192,  t2*64+32, 8, avB,bvA,1, "")     \
        PH(avB,1,1,0, 0,bvA, Ast, sA+16384, t3*64,    4, avA,bvB,1,         \
           "s_waitcnt vmcnt(6)")                                            \
        PH(avA,0,0,0, 1,bvA, Bst, sB+16384, t3*64,    8, avB,bvB,0,         \
           "s_waitcnt vmcnt(4)")                                            \
    }                                                                       \
    asm volatile("s_waitcnt vmcnt(0) lgkmcnt(0)");                          \
    __builtin_amdgcn_sched_barrier(0);                                      \
    __builtin_amdgcn_s_barrier();

// ---------------------------------------------------------------------------
// GEMM1 (qkv): M=65536, N=1536, K=512.  q part pre-scaled by 1/sqrt(HD).
// Epilogue via swizzled LDS C-tile -> 16B stores.
// ---------------------------------------------------------------------------
__global__ __launch_bounds__(512, 2) void gemm1_qkv8(
    const bf16* __restrict__ A, const bf16* __restrict__ B,
    const float* __restrict__ bias, bf16* __restrict__ Cq,
    bf16* __restrict__ Ckv)
{
    GEMM_PREAMBLE
    // XCD-chunked bijective swizzle (nwg=1536=8*192), N-fastest in chunk
    const int bid = blockIdx.x;
    const int wg  = (bid & 7) * 192 + (bid >> 3);
    const long bM = (long)(wg / 6) * 256;
    const long bN = (long)(wg % 6) * 256;

    GEMM_MAIN(A, B)

    const bool isQ = (bN < 512);                   // block-uniform
    const float sc = isQ ? 0.17677669529663687f : 1.0f;  // fold attn scale
    bf16* ct = (bf16*)smemraw;
#pragma unroll
    for (int j = 0; j < 4; ++j) {
        const int col  = wn64 + j * 16 + r16;
        const float bvv = bias[bN + col];
        const int chunk = col >> 3, cl = col & 7;
#pragma unroll
        for (int i = 0; i < 8; ++i)
#pragma unroll
            for (int r = 0; r < 4; ++r) {
                const int row = wm128 + i * 16 + q * 4 + r;
                ct[row * 256 + ((chunk ^ ((row >> 2) & 7)) << 3) + cl] =
                    (bf16)((acc[i][j][r] + bvv) * sc);
            }
    }
    __syncthreads();

    bf16* __restrict__ outp = isQ ? (Cq + bM * 512 + bN)
                                  : (Ckv + bM * 1024 + (bN - 512));
    const int ostr = isQ ? 512 : 1024;
#pragma unroll
    for (int it = 0; it < 16; ++it) {
        const int row = w * 32 + it * 2 + (lane >> 5);  // 2 full rows / wave
        const int c   = lane & 31;
        uint4 v = *(const uint4*)(ct + row * 256 +
                                  ((c ^ ((row >> 2) & 7)) << 3));
        *(uint4*)(outp + (long)row * ostr + c * 8) = v;
    }
}

// ---------------------------------------------------------------------------
// GEMM2 (proj): M=65536, N=512, K=512.  Same template; direct fp32 epilogue.
// ---------------------------------------------------------------------------
__global__ __launch_bounds__(512, 2) void gemm2_proj8(
    const bf16* __restrict__ A, const bf16* __restrict__ B,
    const float* __restrict__ bias, float* __restrict__ C)
{
    GEMM_PREAMBLE
    // nwg=512 = 8*64; 2 N-blocks per M-panel, N-fastest in chunk
    const int bid = blockIdx.x;
    const int wg  = (bid & 7) * 64 + (bid >> 3);
    const long bM = (long)(wg >> 1) * 256;
    const long bN = (long)(wg & 1) * 256;

    GEMM_MAIN(A, B)

#pragma unroll
    for (int j = 0; j < 4; ++j) {
        const long col = bN + wn64 + j * 16 + r16;
        const float bvv = bias[col];
#pragma unroll
        for (int i = 0; i < 8; ++i) {
            const long row = bM + wm128 + i * 16 + q * 4;
#pragma unroll
            for (int r = 0; r < 4; ++r)
                C[(row + r) * 512L + col] = acc[i][j][r] + bvv;
        }
    }
}

// ---------------------------------------------------------------------------
// Window attention: 4 heads (4 waves) per block; one window per block row.
// qbuf: (65536,512) bf16 = q (pre-scaled); kv: (65536,1024) bf16 = [k | v].
// Q/K tiles use the corrected (row>>2)&3 chunk swizzle (same derivation as
// the GEMMs); P/V tiles keep their row&7 key (row stride 128 B there, and
// the colliding set is r16 vs r16+8 -> 2-way = free already).
// ---------------------------------------------------------------------------
__global__ __launch_bounds__(256) void attn_kernel4(
    bf16* __restrict__ qbuf, const bf16* __restrict__ kv,
    const float* __restrict__ mask, const float* __restrict__ bias)
{
    __shared__ __attribute__((aligned(16))) bf16 smem[24576];  // 48 KB
    const int t    = threadIdx.x;
    const int wv   = t >> 6;                 // local head 0..3
    const int lane = t & 63;
    const int q    = lane >> 4;
    const int r16  = lane & 15;
    const int bw   = blockIdx.x >> 2;        // window 0..1023
    const int hg   = blockIdx.x & 3;         // head group
    const int h    = hg * 4 + wv;
    const int nw   = bw & 63;
    const long rowbase = (long)bw * 64;

    bf16* Qs = smem + wv * 6144;   // [64][32] chunk-swizzled (key=(row>>2)&3)
    bf16* Ks = Qs + 2048;          // [64][32]
    bf16* Vt = Qs + 4096;          // [32][64] chunk-swizzled (key=row&7)
    bf16* Ps = Qs;                 // [64][64] chunk-swizzled (key=row&7)

    // stage Q,K (own head): pre-swizzled global chunk source
    const int sc8 = (((lane & 3) ^ ((lane >> 4) & 3)) << 3);
#pragma unroll
    for (int it = 0; it < 4; ++it) {
        const int tok = it * 16 + (lane >> 2);
        gld_lds16(qbuf + (rowbase + tok) * 512  + h * 32 + sc8, Qs + it * 512);
        gld_lds16(kv   + (rowbase + tok) * 1024 + h * 32 + sc8, Ks + it * 512);
    }
    // V row `lane` -> regs -> transposed+swizzled Vt
    {
        const bf16* gv = kv + (rowbase + lane) * 1024 + 512 + h * 32;
        uint4 vtmp[4];
#pragma unroll
        for (int jj = 0; jj < 4; ++jj) vtmp[jj] = ((const uint4*)gv)[jj];
        const bf16* vrow = (const bf16*)vtmp;
        const int tchunk = lane >> 3, tin = lane & 7;
#pragma unroll
        for (int hd = 0; hd < 32; ++hd)
            Vt[hd * 64 + ((tchunk ^ (hd & 7)) << 3) + tin] = vrow[hd];
    }
    asm volatile("s_waitcnt vmcnt(0)" ::: "memory");
    // no __syncthreads: each wave reads only its own head's region; DS ops
    // within a wave execute in order.

    const int cq8 = ((q ^ ((r16 >> 2) & 3)) << 3);
    f32x4 acc[4][4];
    {
        bf16x8 av[4], bv[4];
#pragma unroll
        for (int ti = 0; ti < 4; ++ti)
            av[ti] = *(const bf16x8*)&Qs[(ti * 16 + r16) * 32 + cq8];
#pragma unroll
        for (int tj = 0; tj < 4; ++tj)
            bv[tj] = *(const bf16x8*)&Ks[(tj * 16 + r16) * 32 + cq8];
        const f32x4 z = f32x4{0.f, 0.f, 0.f, 0.f};
#pragma unroll
        for (int ti = 0; ti < 4; ++ti)
#pragma unroll
            for (int tj = 0; tj < 4; ++tj)
                acc[ti][tj] = __builtin_amdgcn_mfma_f32_16x16x32_bf16(
                    av[ti], bv[tj], z, 0, 0, 0);
    }

    const float LOG2E  = 1.4426950408889634f;
    const float* biasH = bias + h * 4096;
    const float* maskW = mask + nw * 4096;

#pragma unroll
    for (int ti = 0; ti < 4; ++ti) {
#pragma unroll
        for (int r = 0; r < 4; ++r) {
            const int row = ti * 16 + q * 4 + r;
            float mx = -1e30f;
#pragma unroll
            for (int tj = 0; tj < 4; ++tj) {
                const int col = tj * 16 + r16;
                float s = acc[ti][tj][r]
                        + biasH[row * 64 + col] + maskW[row * 64 + col];
                acc[ti][tj][r] = s;
                mx = fmaxf(mx, s);
            }
#pragma unroll
            for (int d = 1; d < 16; d <<= 1)
                mx = fmaxf(mx, __shfl_xor(mx, d, 16));
            float sum = 0.f;
#pragma unroll
            for (int tj = 0; tj < 4; ++tj) {
                float e = exp2f((acc[ti][tj][r] - mx) * LOG2E);
                acc[ti][tj][r] = e;
                sum += e;
            }
#pragma unroll
            for (int d = 1; d < 16; d <<= 1)
                sum += __shfl_xor(sum, d, 16);
            const float inv = 1.0f / sum;
#pragma unroll
            for (int tj = 0; tj < 4; ++tj) {
                const int c = tj * 16 + r16;
                Ps[row * 64 + ((((c >> 3) ^ (row & 7)) << 3) + (c & 7))] =
                    (bf16)(acc[ti][tj][r] * inv);
            }
        }
    }

    f32x4 o[4][2];
#pragma unroll
    for (int ti = 0; ti < 4; ++ti)
#pragma unroll
        for (int tn = 0; tn < 2; ++tn)
            o[ti][tn] = f32x4{0.f, 0.f, 0.f, 0.f};

#pragma unroll
    for (int ks = 0; ks < 2; ++ks) {
        bf16x8 av[4], bv[2];
        const int ch = (((ks * 4 + q) ^ (r16 & 7)) << 3);
#pragma unroll
        for (int ti = 0; ti < 4; ++ti)
            av[ti] = *(const bf16x8*)&Ps[(ti * 16 + r16) * 64 + ch];
#pragma unroll
        for (int tn = 0; tn < 2; ++tn)
            bv[tn] = *(const bf16x8*)&Vt[(tn * 16 + r16) * 64 + ch];
#pragma unroll
        for (int ti = 0; ti < 4; ++ti)
#pragma unroll
            for (int tn = 0; tn < 2; ++tn)
                o[ti][tn] = __builtin_amdgcn_mfma_f32_16x16x32_bf16(
                    av[ti], bv[tn], o[ti][tn], 0, 0, 0);
    }

    // stage o into LDS (plain [64][32] at region base; P is dead now)
#pragma unroll
    for (int ti = 0; ti < 4; ++ti)
#pragma unroll
        for (int tn = 0; tn < 2; ++tn)
#pragma unroll
            for (int r = 0; r < 4; ++r)
                Qs[(ti * 16 + q * 4 + r) * 32 + tn * 16 + r16] =
                    (bf16)(o[ti][tn][r]);
    __syncthreads();

    // cooperative coalesced store: 64 rows x 128 cols (4 heads) bf16
    bf16* op = qbuf + rowbase * 512 + hg * 128;
#pragma unroll
    for (int it = 0; it < 4; ++it) {
        const int idx = it * 256 + t;            // 0..1023 16B-chunks
        const int row = idx >> 4;
        const int c   = idx & 15;
        const int hl  = c >> 2;
        uint4 v = *(const uint4*)(smem + hl * 6144 + row * 32 + (c & 3) * 8);
        *(uint4*)(op + (long)row * 512 + hl * 32 + (c & 3) * 8) = v;
    }
}

// ---------------------------------------------------------------------------
extern "C" void kernel_launch(void* const* d_in, const int* in_sizes, int n_in,
                              void* d_out, int out_size, void* d_ws, size_t ws_size,
                              hipStream_t stream) {
    const float* x      = (const float*)d_in[0];
    const float* mask   = (const float*)d_in[1];
    const float* qkv_w  = (const float*)d_in[2];
    const float* qkv_b  = (const float*)d_in[3];
    const float* table  = (const float*)d_in[4];
    const float* proj_w = (const float*)d_in[5];
    const float* proj_b = (const float*)d_in[6];
    const int*   relidx = (const int*)d_in[7];
    float* out = (float*)d_out;

    // ws layout (bytes):
    //   bias  @ 0          256 KB   fp32 (NH,64,64)
    //   qbuf  @ 262144     67.1 MB  bf16 q (pre-scaled), then attn-out in place
    //   xbf   @ 67371008   67.1 MB  bf16 x
    //   wq    @ 134479872  1.57 MB  bf16 qkv_w
    //   wp    @ 136052736  0.52 MB  bf16 proj_w
    //   kv    @ 136577024  134.2 MB bf16 [k|v]  (or aliased to d_out if ws small)
    char*  ws   = (char*)d_ws;
    float* bias = (float*)ws;
    bf16*  qbuf = (bf16*)(ws + 262144);
    bf16*  xbf  = (bf16*)(ws + 67371008);
    bf16*  wq   = (bf16*)(ws + 134479872);
    bf16*  wp   = (bf16*)(ws + 136052736);
    const size_t need_full = 136577024ull + 134217728ull;  // 270.8 MB
    bf16* kvbuf = (ws_size >= need_full) ? (bf16*)(ws + 136577024)
                                         : (bf16*)d_out;

    bias_kernel<<<256, 256, 0, stream>>>(relidx, table, bias);
    cvt_kernel<<<2048, 256, 0, stream>>>(x,      xbf, 8388608);  // 33.5M elems
    cvt_kernel<<<768,  256, 0, stream>>>(qkv_w,  wq,  196608);
    cvt_kernel<<<256,  256, 0, stream>>>(proj_w, wp,  65536);

    gemm1_qkv8<<<1536, 512, 0, stream>>>(xbf, wq, qkv_b, qbuf, kvbuf);
    attn_kernel4<<<4096, 256, 0, stream>>>(qbuf, kvbuf, mask, bias);
    gemm2_proj8<<<512, 512, 0, stream>>>(qbuf, wp, proj_b, out);
}

// Round 4
// 531.511 us; speedup vs baseline: 1.0126x; 1.0126x over previous
//
#include <hip/hip_runtime.h>
#include <hip/hip_bf16.h>

typedef __bf16 bf16;
typedef __bf16 bf16x4 __attribute__((ext_vector_type(4)));
typedef __bf16 bf16x8 __attribute__((ext_vector_type(8)));
typedef float  f32x4  __attribute__((ext_vector_type(4)));

#define AS1 __attribute__((address_space(1)))
#define AS3 __attribute__((address_space(3)))

__device__ __forceinline__ void gld_lds16(const void* g, void* l) {
    // async global->LDS, 16B per lane; LDS dest = wave-uniform base + lane*16
    __builtin_amdgcn_global_load_lds((AS1 void*)g, (AS3 void*)l, 16, 0, 0);
}

// ---------------------------------------------------------------------------
// fp32 -> bf16 bulk convert, float4-vectorized grid-stride
// ---------------------------------------------------------------------------
__global__ void cvt_kernel(const float* __restrict__ in, bf16* __restrict__ out,
                           int n4) {
    for (long i = (long)blockIdx.x * blockDim.x + threadIdx.x; i < n4;
         i += (long)gridDim.x * blockDim.x) {
        f32x4 v = ((const f32x4*)in)[i];
        bf16x4 h;
#pragma unroll
        for (int e = 0; e < 4; ++e) h[e] = (bf16)v[e];
        ((bf16x4*)out)[i] = h;
    }
}

// ---------------------------------------------------------------------------
// bmr[nw][h][row][r16][tj] = (table[relidx[row*64+col]*16+h] + mask[nw][row][col])
//                            * log2(e),   col = tj*16 + r16.
// Permuted so the attn softmax reads ONE float4 per (row, lane) instead of
// 8 scalars (bias+mask separately).  4.19M floats = 16.8 MB.
// ---------------------------------------------------------------------------
__global__ void bmr_kernel(const int* __restrict__ rel_index,
                           const float* __restrict__ table,
                           const float* __restrict__ mask,
                           float* __restrict__ bmr) {
    const float LOG2E = 1.4426950408889634f;
    int idx = blockIdx.x * 256 + threadIdx.x;   // [nw:6][h:4][row:6][r16:4][tj:2]
    int tj  = idx & 3;
    int r16 = (idx >> 2) & 15;
    int row = (idx >> 6) & 63;
    int h   = (idx >> 12) & 15;
    int nw  = idx >> 16;
    int col = tj * 16 + r16;
    bmr[idx] = (table[rel_index[row * 64 + col] * 16 + h]
                + mask[nw * 4096 + row * 64 + col]) * LOG2E;
}

// ---------------------------------------------------------------------------
// Shared 8-phase GEMM machinery (unchanged from round 3 — control).
// LDS tiles [slot][kk][256 rows][32 k] bf16; fragment reads are structurally
// bank-uniform (verified: SQ_LDS_BANK_CONFLICT == staging-DMA fixed cost).
// ---------------------------------------------------------------------------
#define STAGE(GBASE, LBASE, SK0)                                          \
    { _Pragma("unroll")                                                   \
      for (int c_ = 0; c_ < 2; ++c_)                                      \
          gld_lds16((GBASE) + c_ * 16 * 512 + (SK0),                      \
                    (LBASE) + (w * 2 + c_) * 512); }

#define FRAG_A(DST, S, KK, IH)                                              \
  { const bf16* ap_ = sA + ((S)*2+(KK))*8192 + (wm128+(IH)*64+r16)*32 + cq8;\
    _Pragma("unroll")                                                       \
    for (int ii_ = 0; ii_ < 4; ++ii_)                                       \
        DST[ii_] = *(const bf16x8*)(ap_ + ii_*512); }

#define FRAG_B(DST, S, KK)                                                  \
  { const bf16* bp_ = sB + ((S)*2+(KK))*8192 + (wn64+r16)*32 + cq8;         \
    _Pragma("unroll")                                                       \
    for (int jj_ = 0; jj_ < 4; ++jj_)                                       \
        DST[jj_] = *(const bf16x8*)(bp_ + jj_*512); }

#define PH(PFAD, PFS, PFKK, PFIH, PFB, PFBD, GB, LB, SK0, LGK, UAV, UBV,    \
           UIH, VMA)                                                        \
  { FRAG_A(PFAD, PFS, PFKK, PFIH);                                          \
    if (PFB) FRAG_B(PFBD, PFS, PFKK);                                       \
    STAGE(GB, LB, SK0);                                                     \
    __builtin_amdgcn_sched_barrier(0);                                      \
    __builtin_amdgcn_s_barrier();                                           \
    asm volatile("s_waitcnt lgkmcnt(" #LGK ")");                            \
    __builtin_amdgcn_sched_barrier(0);                                      \
    __builtin_amdgcn_s_setprio(1);                                          \
    _Pragma("unroll")                                                       \
    for (int ii_ = 0; ii_ < 4; ++ii_)                                       \
      _Pragma("unroll")                                                     \
      for (int jj_ = 0; jj_ < 4; ++jj_)                                     \
        acc[(UIH)*4+ii_][jj_] = __builtin_amdgcn_mfma_f32_16x16x32_bf16(    \
            UAV[ii_], UBV[jj_], acc[(UIH)*4+ii_][jj_], 0, 0, 0);            \
    __builtin_amdgcn_s_setprio(0);                                          \
    asm volatile(VMA);                                                      \
    __builtin_amdgcn_sched_barrier(0);                                      \
    __builtin_amdgcn_s_barrier(); }

#define GEMM_PREAMBLE                                                       \
    __shared__ __attribute__((aligned(16))) char smemraw[131072];           \
    bf16* sA = (bf16*)smemraw;                                              \
    bf16* sB = sA + 32768;                                                  \
    const int t     = threadIdx.x;                                          \
    const int w     = t >> 6;                                               \
    const int lane  = t & 63;                                               \
    const int q     = lane >> 4;                                            \
    const int r16   = lane & 15;                                            \
    const int wm128 = (w >> 2) * 128;                                       \
    const int wn64  = (w & 3) * 64;                                         \
    const int sc8   = (((lane & 3) ^ ((lane >> 4) & 3)) << 3);              \
    const int cq8   = ((q ^ ((r16 >> 2) & 3)) << 3);

#define GEMM_MAIN(ABASE, BBASE)                                             \
    const bf16* Ast = (ABASE) + (bM + w * 32 + (lane >> 2)) * 512 + sc8;    \
    const bf16* Bst = (BBASE) + (bN + w * 32 + (lane >> 2)) * 512 + sc8;    \
    f32x4 acc[8][4];                                                        \
    _Pragma("unroll")                                                       \
    for (int i = 0; i < 8; ++i)                                             \
        _Pragma("unroll")                                                   \
        for (int j = 0; j < 4; ++j) acc[i][j] = f32x4{0.f, 0.f, 0.f, 0.f};  \
    bf16x8 avA[4], avB[4], bvA[4], bvB[4];                                  \
    STAGE(Ast, sA + 0,     0);                                              \
    STAGE(Bst, sB + 0,     0);                                              \
    STAGE(Ast, sA + 8192,  32);                                             \
    STAGE(Bst, sB + 8192,  32);                                             \
    STAGE(Ast, sA + 16384, 64);                                             \
    STAGE(Bst, sB + 16384, 64);                                             \
    asm volatile("s_waitcnt vmcnt(4)");                                     \
    __builtin_amdgcn_sched_barrier(0);                                      \
    __builtin_amdgcn_s_barrier();                                           \
    FRAG_A(avA, 0, 0, 0);                                                   \
    FRAG_B(bvA, 0, 0);                                                      \
    for (int i = 0; i < 4; ++i) {                                           \
        const int t1 = 2 * i + 1;                                           \
        const int t2 = (2 * i + 2 < 8) ? 2 * i + 2 : 7;                     \
        const int t3 = (2 * i + 3 < 8) ? 2 * i + 3 : 7;                     \
        PH(avB,0,0,1, 0,bvB, Ast, sA+24576, t1*64+32, 4, avA,bvA,0, "")     \
        PH(avA,0,1,1, 1,bvB, Bst, sB+24576, t1*64+32, 8, avB,bvA,1, "")     \
        PH(avB,0,1,0, 0,bvA, Ast, sA+0,     t2*64,    4, avA,bvB,1,         \
           "s_waitcnt vmcnt(6)")                                            \
        PH(avA,1,0,0, 1,bvA, Bst, sB+0,     t2*64,    8, avB,bvB,0, "")     \
        PH(avB,1,0,1, 0,bvB, Ast, sA+8192,  t2*64+32, 4, avA,bvA,0,         \
           "s_waitcnt vmcnt(6)")                                            \
        PH(avA,1,1,1, 1,bvB, Bst, sB+8192,  t2*64+32, 8, avB,bvA,1, "")     \
        PH(avB,1,1,0, 0,bvA, Ast, sA+16384, t3*64,    4, avA,bvB,1,         \
           "s_waitcnt vmcnt(6)")                                            \
        PH(avA,0,0,0, 1,bvA, Bst, sB+16384, t3*64,    8, avB,bvB,0,         \
           "s_waitcnt vmcnt(4)")                                            \
    }                                                                       \
    asm volatile("s_waitcnt vmcnt(0) lgkmcnt(0)");                          \
    __builtin_amdgcn_sched_barrier(0);                                      \
    __builtin_amdgcn_s_barrier();

// ---------------------------------------------------------------------------
// GEMM1 (qkv): M=65536, N=1536, K=512.  q part pre-scaled by log2e/sqrt(HD)
// (folds both the attention scale and the exp->exp2 conversion).
// ---------------------------------------------------------------------------
__global__ __launch_bounds__(512, 2) void gemm1_qkv8(
    const bf16* __restrict__ A, const bf16* __restrict__ B,
    const float* __restrict__ bias, bf16* __restrict__ Cq,
    bf16* __restrict__ Ckv)
{
    GEMM_PREAMBLE
    // XCD-chunked bijective swizzle (nwg=1536=8*192), N-fastest in chunk
    const int bid = blockIdx.x;
    const int wg  = (bid & 7) * 192 + (bid >> 3);
    const long bM = (long)(wg / 6) * 256;
    const long bN = (long)(wg % 6) * 256;

    GEMM_MAIN(A, B)

    const bool isQ = (bN < 512);                   // block-uniform
    const float sc = isQ ? 0.25503486f : 1.0f;     // log2e / sqrt(32)
    bf16* ct = (bf16*)smemraw;
#pragma unroll
    for (int j = 0; j < 4; ++j) {
        const int col  = wn64 + j * 16 + r16;
        const float bvv = bias[bN + col];
        const int chunk = col >> 3, cl = col & 7;
#pragma unroll
        for (int i = 0; i < 8; ++i)
#pragma unroll
            for (int r = 0; r < 4; ++r) {
                const int row = wm128 + i * 16 + q * 4 + r;
                ct[row * 256 + ((chunk ^ ((row >> 2) & 7)) << 3) + cl] =
                    (bf16)((acc[i][j][r] + bvv) * sc);
            }
    }
    __syncthreads();

    bf16* __restrict__ outp = isQ ? (Cq + bM * 512 + bN)
                                  : (Ckv + bM * 1024 + (bN - 512));
    const int ostr = isQ ? 512 : 1024;
#pragma unroll
    for (int it = 0; it < 16; ++it) {
        const int row = w * 32 + it * 2 + (lane >> 5);  // 2 full rows / wave
        const int c   = lane & 31;
        uint4 v = *(const uint4*)(ct + row * 256 +
                                  ((c ^ ((row >> 2) & 7)) << 3));
        *(uint4*)(outp + (long)row * ostr + c * 8) = v;
    }
}

// ---------------------------------------------------------------------------
// GEMM2 (proj): M=65536, N=512, K=512.  fp32 epilogue now staged through LDS
// (two 128-row halves, chunk-XOR key (row>>2)&7 -> 2-way free both sides),
// stores are 1-KB coalesced dwordx4 instead of 128 scalar 4-B stores.
// ---------------------------------------------------------------------------
__global__ __launch_bounds__(512, 2) void gemm2_proj8(
    const bf16* __restrict__ A, const bf16* __restrict__ B,
    const float* __restrict__ bias, float* __restrict__ C)
{
    GEMM_PREAMBLE
    // nwg=512 = 8*64; 2 N-blocks per M-panel, N-fastest in chunk
    const int bid = blockIdx.x;
    const int wg  = (bid & 7) * 64 + (bid >> 3);
    const long bM = (long)(wg >> 1) * 256;
    const long bN = (long)(wg & 1) * 256;

    GEMM_MAIN(A, B)

    float* ct32 = (float*)smemraw;   // [128][256] fp32 = 128 KB
#pragma unroll
    for (int half = 0; half < 2; ++half) {
        __syncthreads();
        if ((w >> 2) == half) {
#pragma unroll
            for (int j = 0; j < 4; ++j) {
                const int col  = wn64 + j * 16 + r16;
                const float bvv = bias[bN + col];
#pragma unroll
                for (int i = 0; i < 8; ++i)
#pragma unroll
                    for (int r = 0; r < 4; ++r) {
                        const int row = i * 16 + q * 4 + r;   // 0..127
                        ct32[row * 256 + (col ^ (((row >> 2) & 7) << 2))] =
                            acc[i][j][r] + bvv;
                    }
            }
        }
        __syncthreads();
#pragma unroll
        for (int it = 0; it < 16; ++it) {
            const int row = it * 8 + w;                        // 0..127
            f32x4 v = *(const f32x4*)&ct32[row * 256 +
                                           ((lane * 4) ^ (((row >> 2) & 7) << 2))];
            *(f32x4*)(C + (bM + half * 128 + row) * 512L + bN + lane * 4) = v;
        }
    }
}

// ---------------------------------------------------------------------------
// Window attention: 4 heads (4 waves) per block; one window per block.
// qbuf: (65536,512) bf16 = q (pre-scaled by log2e/sqrt(32));
// kv: (65536,1024) bf16 = [k | v]; bmr: combined (bias+mask)*log2e, permuted
// [nw][h][row][r16][tj] so softmax does 16 coalesced float4 loads per lane.
// ---------------------------------------------------------------------------
__global__ __launch_bounds__(256) void attn_kernel4(
    bf16* __restrict__ qbuf, const bf16* __restrict__ kv,
    const float* __restrict__ bmr)
{
    __shared__ __attribute__((aligned(16))) bf16 smem[24576];  // 48 KB
    const int t    = threadIdx.x;
    const int wv   = t >> 6;                 // local head 0..3
    const int lane = t & 63;
    const int q    = lane >> 4;
    const int r16  = lane & 15;
    const int bw   = blockIdx.x >> 2;        // window 0..1023
    const int hg   = blockIdx.x & 3;         // head group
    const int h    = hg * 4 + wv;
    const int nw   = bw & 63;
    const long rowbase = (long)bw * 64;

    bf16* Qs = smem + wv * 6144;   // [64][32] chunk-swizzled
    bf16* Ks = Qs + 2048;          // [64][32]
    bf16* Vt = Qs + 4096;          // [32][64] chunk-swizzled (key=row&7)
    bf16* Ps = Qs;                 // [64][64] reuses Q+K after QK^T

    // stage Q,K (own head): pre-swizzled global chunk source
    const int sc8 = (((lane & 3) ^ ((lane >> 4) & 3)) << 3);
#pragma unroll
    for (int it = 0; it < 4; ++it) {
        const int tok = it * 16 + (lane >> 2);
        gld_lds16(qbuf + (rowbase + tok) * 512  + h * 32 + sc8, Qs + it * 512);
        gld_lds16(kv   + (rowbase + tok) * 1024 + h * 32 + sc8, Ks + it * 512);
    }
    // V row `lane` -> regs -> transposed+swizzled Vt
    {
        const bf16* gv = kv + (rowbase + lane) * 1024 + 512 + h * 32;
        uint4 vtmp[4];
#pragma unroll
        for (int jj = 0; jj < 4; ++jj) vtmp[jj] = ((const uint4*)gv)[jj];
        const bf16* vrow = (const bf16*)vtmp;
        const int tchunk = lane >> 3, tin = lane & 7;
#pragma unroll
        for (int hd = 0; hd < 32; ++hd)
            Vt[hd * 64 + ((tchunk ^ (hd & 7)) << 3) + tin] = vrow[hd];
    }
    asm volatile("s_waitcnt vmcnt(0)" ::: "memory");
    // no __syncthreads: each wave reads only its own head's region.

    const int cq8 = ((q ^ ((r16 >> 2) & 3)) << 3);
    f32x4 acc[4][4];
    {
        bf16x8 av[4], bv[4];
#pragma unroll
        for (int ti = 0; ti < 4; ++ti)
            av[ti] = *(const bf16x8*)&Qs[(ti * 16 + r16) * 32 + cq8];
#pragma unroll
        for (int tj = 0; tj < 4; ++tj)
            bv[tj] = *(const bf16x8*)&Ks[(tj * 16 + r16) * 32 + cq8];
        const f32x4 z = f32x4{0.f, 0.f, 0.f, 0.f};
#pragma unroll
        for (int ti = 0; ti < 4; ++ti)
#pragma unroll
            for (int tj = 0; tj < 4; ++tj)
                acc[ti][tj] = __builtin_amdgcn_mfma_f32_16x16x32_bf16(
                    av[ti], bv[tj], z, 0, 0, 0);
    }

    // softmax in log2-units: scores already *log2e (q pre-scale + bmr)
    const float* bmw = bmr + ((long)(nw * 16 + h) << 12);
#pragma unroll
    for (int ti = 0; ti < 4; ++ti) {
        f32x4 bm4[4];
#pragma unroll
        for (int r = 0; r < 4; ++r)
            bm4[r] = *(const f32x4*)(bmw + (ti * 16 + q * 4 + r) * 64 + r16 * 4);
#pragma unroll
        for (int r = 0; r < 4; ++r) {
            const int row = ti * 16 + q * 4 + r;
            float mx = -1e30f;
#pragma unroll
            for (int tj = 0; tj < 4; ++tj) {
                float s = acc[ti][tj][r] + bm4[r][tj];
                acc[ti][tj][r] = s;
                mx = fmaxf(mx, s);
            }
#pragma unroll
            for (int d = 1; d < 16; d <<= 1)
                mx = fmaxf(mx, __shfl_xor(mx, d, 16));
            float sum = 0.f;
#pragma unroll
            for (int tj = 0; tj < 4; ++tj) {
                float e = exp2f(acc[ti][tj][r] - mx);
                acc[ti][tj][r] = e;
                sum += e;
            }
#pragma unroll
            for (int d = 1; d < 16; d <<= 1)
                sum += __shfl_xor(sum, d, 16);
            const float inv = 1.0f / sum;
#pragma unroll
            for (int tj = 0; tj < 4; ++tj) {
                const int c = tj * 16 + r16;
                Ps[row * 64 + ((((c >> 3) ^ (row & 7)) << 3) + (c & 7))] =
                    (bf16)(acc[ti][tj][r] * inv);
            }
        }
    }

    f32x4 o[4][2];
#pragma unroll
    for (int ti = 0; ti < 4; ++ti)
#pragma unroll
        for (int tn = 0; tn < 2; ++tn)
            o[ti][tn] = f32x4{0.f, 0.f, 0.f, 0.f};

#pragma unroll
    for (int ks = 0; ks < 2; ++ks) {
        bf16x8 av[4], bv[2];
        const int ch = (((ks * 4 + q) ^ (r16 & 7)) << 3);
#pragma unroll
        for (int ti = 0; ti < 4; ++ti)
            av[ti] = *(const bf16x8*)&Ps[(ti * 16 + r16) * 64 + ch];
#pragma unroll
        for (int tn = 0; tn < 2; ++tn)
            bv[tn] = *(const bf16x8*)&Vt[(tn * 16 + r16) * 64 + ch];
#pragma unroll
        for (int ti = 0; ti < 4; ++ti)
#pragma unroll
            for (int tn = 0; tn < 2; ++tn)
                o[ti][tn] = __builtin_amdgcn_mfma_f32_16x16x32_bf16(
                    av[ti], bv[tn], o[ti][tn], 0, 0, 0);
    }

    // stage o into LDS (plain [64][32] at region base; P is dead now)
#pragma unroll
    for (int ti = 0; ti < 4; ++ti)
#pragma unroll
        for (int tn = 0; tn < 2; ++tn)
#pragma unroll
            for (int r = 0; r < 4; ++r)
                Qs[(ti * 16 + q * 4 + r) * 32 + tn * 16 + r16] =
                    (bf16)(o[ti][tn][r]);
    __syncthreads();

    // cooperative coalesced store: 64 rows x 128 cols (4 heads) bf16
    bf16* op = qbuf + rowbase * 512 + hg * 128;
#pragma unroll
    for (int it = 0; it < 4; ++it) {
        const int idx = it * 256 + t;            // 0..1023 16B-chunks
        const int row = idx >> 4;
        const int c   = idx & 15;
        const int hl  = c >> 2;
        uint4 v = *(const uint4*)(smem + hl * 6144 + row * 32 + (c & 3) * 8);
        *(uint4*)(op + (long)row * 512 + hl * 32 + (c & 3) * 8) = v;
    }
}

// ---------------------------------------------------------------------------
extern "C" void kernel_launch(void* const* d_in, const int* in_sizes, int n_in,
                              void* d_out, int out_size, void* d_ws, size_t ws_size,
                              hipStream_t stream) {
    const float* x      = (const float*)d_in[0];
    const float* mask   = (const float*)d_in[1];
    const float* qkv_w  = (const float*)d_in[2];
    const float* qkv_b  = (const float*)d_in[3];
    const float* table  = (const float*)d_in[4];
    const float* proj_w = (const float*)d_in[5];
    const float* proj_b = (const float*)d_in[6];
    const int*   relidx = (const int*)d_in[7];
    float* out = (float*)d_out;

    // ws layout (bytes):
    //   (spare) @ 0        256 KB
    //   qbuf  @ 262144     67.1 MB  bf16 q (pre-scaled), then attn-out in place
    //   xbf   @ 67371008   67.1 MB  bf16 x; REUSED as bmr (16.8 MB fp32) after gemm1
    //   wq    @ 134479872  1.57 MB  bf16 qkv_w
    //   wp    @ 136052736  0.52 MB  bf16 proj_w
    //   kv    @ 136577024  134.2 MB bf16 [k|v]  (or aliased to d_out if ws small)
    char*  ws   = (char*)d_ws;
    bf16*  qbuf = (bf16*)(ws + 262144);
    bf16*  xbf  = (bf16*)(ws + 67371008);
    float* bmr  = (float*)(ws + 67371008);   // aliases xbf (dead after gemm1)
    bf16*  wq   = (bf16*)(ws + 134479872);
    bf16*  wp   = (bf16*)(ws + 136052736);
    const size_t need_full = 136577024ull + 134217728ull;  // 270.8 MB
    bf16* kvbuf = (ws_size >= need_full) ? (bf16*)(ws + 136577024)
                                         : (bf16*)d_out;

    cvt_kernel<<<2048, 256, 0, stream>>>(x,      xbf, 8388608);  // 33.5M elems
    cvt_kernel<<<768,  256, 0, stream>>>(qkv_w,  wq,  196608);
    cvt_kernel<<<256,  256, 0, stream>>>(proj_w, wp,  65536);

    gemm1_qkv8<<<1536, 512, 0, stream>>>(xbf, wq, qkv_b, qbuf, kvbuf);
    bmr_kernel<<<16384, 256, 0, stream>>>(relidx, table, mask, bmr);
    attn_kernel4<<<4096, 256, 0, stream>>>(qbuf, kvbuf, bmr);
    gemm2_proj8<<<512, 512, 0, stream>>>(qbuf, wp, proj_b, out);
}

// Round 5
// 515.326 us; speedup vs baseline: 1.0444x; 1.0314x over previous
//
#include <hip/hip_runtime.h>
#include <hip/hip_bf16.h>

typedef __bf16 bf16;
typedef __bf16 bf16x4 __attribute__((ext_vector_type(4)));
typedef __bf16 bf16x8 __attribute__((ext_vector_type(8)));
typedef float  f32x4  __attribute__((ext_vector_type(4)));

#define AS1 __attribute__((address_space(1)))
#define AS3 __attribute__((address_space(3)))

__device__ __forceinline__ void gld_lds16(const void* g, void* l) {
    // async global->LDS, 16B per lane; LDS dest = wave-uniform base + lane*16
    __builtin_amdgcn_global_load_lds((AS1 void*)g, (AS3 void*)l, 16, 0, 0);
}

// ---------------------------------------------------------------------------
// fp32 -> bf16 bulk convert, float4-vectorized grid-stride
// ---------------------------------------------------------------------------
__global__ void cvt_kernel(const float* __restrict__ in, bf16* __restrict__ out,
                           int n4) {
    for (long i = (long)blockIdx.x * blockDim.x + threadIdx.x; i < n4;
         i += (long)gridDim.x * blockDim.x) {
        f32x4 v = ((const f32x4*)in)[i];
        bf16x4 h;
#pragma unroll
        for (int e = 0; e < 4; ++e) h[e] = (bf16)v[e];
        ((bf16x4*)out)[i] = h;
    }
}

// ---------------------------------------------------------------------------
// bmr: combined (bias + mask) * log2e, permuted for the SWAPPED-QK^T lane
// layout: bmr[nw][h][tq*4+tk][lane][r], where the score held by `lane`
// (q=lane>>4, r16=lane&15) in acc[tk][tq][r] is
//   S[k = tk*16 + q*4 + r][qrow = tq*16 + r16].
// Per (tq,tk) a wave reads 64 lanes x 16 B = 1 KB contiguous.
// ---------------------------------------------------------------------------
__global__ void bmr_kernel(const int* __restrict__ rel_index,
                           const float* __restrict__ table,
                           const float* __restrict__ mask,
                           float* __restrict__ bmr) {
    const float LOG2E = 1.4426950408889634f;
    int idx = blockIdx.x * 256 + threadIdx.x;   // [nw:6][h:4][tq:2][tk:2][ln:6][r:2]
    int r   = idx & 3;
    int ln  = (idx >> 2) & 63;
    int tk  = (idx >> 8) & 3;
    int tq  = (idx >> 10) & 3;
    int h   = (idx >> 12) & 15;
    int nw  = idx >> 16;
    int row = tq * 16 + (ln & 15);          // q-row
    int col = tk * 16 + (ln >> 4) * 4 + r;  // k index
    bmr[idx] = (table[rel_index[row * 64 + col] * 16 + h]
                + mask[nw * 4096 + row * 64 + col]) * LOG2E;
}

// ---------------------------------------------------------------------------
// Shared 8-phase GEMM machinery (frozen control since round 3).
// ---------------------------------------------------------------------------
#define STAGE(GBASE, LBASE, SK0)                                          \
    { _Pragma("unroll")                                                   \
      for (int c_ = 0; c_ < 2; ++c_)                                      \
          gld_lds16((GBASE) + c_ * 16 * 512 + (SK0),                      \
                    (LBASE) + (w * 2 + c_) * 512); }

#define FRAG_A(DST, S, KK, IH)                                              \
  { const bf16* ap_ = sA + ((S)*2+(KK))*8192 + (wm128+(IH)*64+r16)*32 + cq8;\
    _Pragma("unroll")                                                       \
    for (int ii_ = 0; ii_ < 4; ++ii_)                                       \
        DST[ii_] = *(const bf16x8*)(ap_ + ii_*512); }

#define FRAG_B(DST, S, KK)                                                  \
  { const bf16* bp_ = sB + ((S)*2+(KK))*8192 + (wn64+r16)*32 + cq8;         \
    _Pragma("unroll")                                                       \
    for (int jj_ = 0; jj_ < 4; ++jj_)                                       \
        DST[jj_] = *(const bf16x8*)(bp_ + jj_*512); }

#define PH(PFAD, PFS, PFKK, PFIH, PFB, PFBD, GB, LB, SK0, LGK, UAV, UBV,    \
           UIH, VMA)                                                        \
  { FRAG_A(PFAD, PFS, PFKK, PFIH);                                          \
    if (PFB) FRAG_B(PFBD, PFS, PFKK);                                       \
    STAGE(GB, LB, SK0);                                                     \
    __builtin_amdgcn_sched_barrier(0);                                      \
    __builtin_amdgcn_s_barrier();                                           \
    asm volatile("s_waitcnt lgkmcnt(" #LGK ")");                            \
    __builtin_amdgcn_sched_barrier(0);                                      \
    __builtin_amdgcn_s_setprio(1);                                          \
    _Pragma("unroll")                                                       \
    for (int ii_ = 0; ii_ < 4; ++ii_)                                       \
      _Pragma("unroll")                                                     \
      for (int jj_ = 0; jj_ < 4; ++jj_)                                     \
        acc[(UIH)*4+ii_][jj_] = __builtin_amdgcn_mfma_f32_16x16x32_bf16(    \
            UAV[ii_], UBV[jj_], acc[(UIH)*4+ii_][jj_], 0, 0, 0);            \
    __builtin_amdgcn_s_setprio(0);                                          \
    asm volatile(VMA);                                                      \
    __builtin_amdgcn_sched_barrier(0);                                      \
    __builtin_amdgcn_s_barrier(); }

#define GEMM_PREAMBLE                                                       \
    __shared__ __attribute__((aligned(16))) char smemraw[131072];           \
    bf16* sA = (bf16*)smemraw;                                              \
    bf16* sB = sA + 32768;                                                  \
    const int t     = threadIdx.x;                                          \
    const int w     = t >> 6;                                               \
    const int lane  = t & 63;                                               \
    const int q     = lane >> 4;                                            \
    const int r16   = lane & 15;                                            \
    const int wm128 = (w >> 2) * 128;                                       \
    const int wn64  = (w & 3) * 64;                                         \
    const int sc8   = (((lane & 3) ^ ((lane >> 4) & 3)) << 3);              \
    const int cq8   = ((q ^ ((r16 >> 2) & 3)) << 3);

#define GEMM_MAIN(ABASE, BBASE)                                             \
    const bf16* Ast = (ABASE) + (bM + w * 32 + (lane >> 2)) * 512 + sc8;    \
    const bf16* Bst = (BBASE) + (bN + w * 32 + (lane >> 2)) * 512 + sc8;    \
    f32x4 acc[8][4];                                                        \
    _Pragma("unroll")                                                       \
    for (int i = 0; i < 8; ++i)                                             \
        _Pragma("unroll")                                                   \
        for (int j = 0; j < 4; ++j) acc[i][j] = f32x4{0.f, 0.f, 0.f, 0.f};  \
    bf16x8 avA[4], avB[4], bvA[4], bvB[4];                                  \
    STAGE(Ast, sA + 0,     0);                                              \
    STAGE(Bst, sB + 0,     0);                                              \
    STAGE(Ast, sA + 8192,  32);                                             \
    STAGE(Bst, sB + 8192,  32);                                             \
    STAGE(Ast, sA + 16384, 64);                                             \
    STAGE(Bst, sB + 16384, 64);                                             \
    asm volatile("s_waitcnt vmcnt(4)");                                     \
    __builtin_amdgcn_sched_barrier(0);                                      \
    __builtin_amdgcn_s_barrier();                                           \
    FRAG_A(avA, 0, 0, 0);                                                   \
    FRAG_B(bvA, 0, 0);                                                      \
    for (int i = 0; i < 4; ++i) {                                           \
        const int t1 = 2 * i + 1;                                           \
        const int t2 = (2 * i + 2 < 8) ? 2 * i + 2 : 7;                     \
        const int t3 = (2 * i + 3 < 8) ? 2 * i + 3 : 7;                     \
        PH(avB,0,0,1, 0,bvB, Ast, sA+24576, t1*64+32, 4, avA,bvA,0, "")     \
        PH(avA,0,1,1, 1,bvB, Bst, sB+24576, t1*64+32, 8, avB,bvA,1, "")     \
        PH(avB,0,1,0, 0,bvA, Ast, sA+0,     t2*64,    4, avA,bvB,1,         \
           "s_waitcnt vmcnt(6)")                                            \
        PH(avA,1,0,0, 1,bvA, Bst, sB+0,     t2*64,    8, avB,bvB,0, "")     \
        PH(avB,1,0,1, 0,bvB, Ast, sA+8192,  t2*64+32, 4, avA,bvA,0,         \
           "s_waitcnt vmcnt(6)")                                            \
        PH(avA,1,1,1, 1,bvB, Bst, sB+8192,  t2*64+32, 8, avB,bvA,1, "")     \
        PH(avB,1,1,0, 0,bvA, Ast, sA+16384, t3*64,    4, avA,bvB,1,         \
           "s_waitcnt vmcnt(6)")                                            \
        PH(avA,0,0,0, 1,bvA, Bst, sB+16384, t3*64,    8, avB,bvB,0,         \
           "s_waitcnt vmcnt(4)")                                            \
    }                                                                       \
    asm volatile("s_waitcnt vmcnt(0) lgkmcnt(0)");                          \
    __builtin_amdgcn_sched_barrier(0);                                      \
    __builtin_amdgcn_s_barrier();

// ---------------------------------------------------------------------------
// GEMM1 (qkv): M=65536, N=1536, K=512.  q part pre-scaled by log2e/sqrt(HD).
// ---------------------------------------------------------------------------
__global__ __launch_bounds__(512, 2) void gemm1_qkv8(
    const bf16* __restrict__ A, const bf16* __restrict__ B,
    const float* __restrict__ bias, bf16* __restrict__ Cq,
    bf16* __restrict__ Ckv)
{
    GEMM_PREAMBLE
    // XCD-chunked bijective swizzle (nwg=1536=8*192), N-fastest in chunk
    const int bid = blockIdx.x;
    const int wg  = (bid & 7) * 192 + (bid >> 3);
    const long bM = (long)(wg / 6) * 256;
    const long bN = (long)(wg % 6) * 256;

    GEMM_MAIN(A, B)

    const bool isQ = (bN < 512);                   // block-uniform
    const float sc = isQ ? 0.25503486f : 1.0f;     // log2e / sqrt(32)
    bf16* ct = (bf16*)smemraw;
#pragma unroll
    for (int j = 0; j < 4; ++j) {
        const int col  = wn64 + j * 16 + r16;
        const float bvv = bias[bN + col];
        const int chunk = col >> 3, cl = col & 7;
#pragma unroll
        for (int i = 0; i < 8; ++i)
#pragma unroll
            for (int r = 0; r < 4; ++r) {
                const int row = wm128 + i * 16 + q * 4 + r;
                ct[row * 256 + ((chunk ^ ((row >> 2) & 7)) << 3) + cl] =
                    (bf16)((acc[i][j][r] + bvv) * sc);
            }
    }
    __syncthreads();

    bf16* __restrict__ outp = isQ ? (Cq + bM * 512 + bN)
                                  : (Ckv + bM * 1024 + (bN - 512));
    const int ostr = isQ ? 512 : 1024;
#pragma unroll
    for (int it = 0; it < 16; ++it) {
        const int row = w * 32 + it * 2 + (lane >> 5);  // 2 full rows / wave
        const int c   = lane & 31;
        uint4 v = *(const uint4*)(ct + row * 256 +
                                  ((c ^ ((row >> 2) & 7)) << 3));
        *(uint4*)(outp + (long)row * ostr + c * 8) = v;
    }
}

// ---------------------------------------------------------------------------
// GEMM2 (proj): M=65536, N=512, K=512.  (frozen control)
// ---------------------------------------------------------------------------
__global__ __launch_bounds__(512, 2) void gemm2_proj8(
    const bf16* __restrict__ A, const bf16* __restrict__ B,
    const float* __restrict__ bias, float* __restrict__ C)
{
    GEMM_PREAMBLE
    // nwg=512 = 8*64; 2 N-blocks per M-panel, N-fastest in chunk
    const int bid = blockIdx.x;
    const int wg  = (bid & 7) * 64 + (bid >> 3);
    const long bM = (long)(wg >> 1) * 256;
    const long bN = (long)(wg & 1) * 256;

    GEMM_MAIN(A, B)

    float* ct32 = (float*)smemraw;   // [128][256] fp32 = 128 KB
#pragma unroll
    for (int half = 0; half < 2; ++half) {
        __syncthreads();
        if ((w >> 2) == half) {
#pragma unroll
            for (int j = 0; j < 4; ++j) {
                const int col  = wn64 + j * 16 + r16;
                const float bvv = bias[bN + col];
#pragma unroll
                for (int i = 0; i < 8; ++i)
#pragma unroll
                    for (int r = 0; r < 4; ++r) {
                        const int row = i * 16 + q * 4 + r;   // 0..127
                        ct32[row * 256 + (col ^ (((row >> 2) & 7) << 2))] =
                            acc[i][j][r] + bvv;
                    }
            }
        }
        __syncthreads();
#pragma unroll
        for (int it = 0; it < 16; ++it) {
            const int row = it * 8 + w;                        // 0..127
            f32x4 v = *(const f32x4*)&ct32[row * 256 +
                                           ((lane * 4) ^ (((row >> 2) & 7) << 2))];
            *(f32x4*)(C + (bM + half * 128 + row) * 512L + bN + lane * 4) = v;
        }
    }
}

// ---------------------------------------------------------------------------
// Window attention, SWAPPED QK^T: acc[tk][tq] = mfma(K_frag, Q_frag) puts a
// full Q-row's scores lane-local per tq (qrow = tq*16 + r16):
//   - row max/sum = 15 in-lane VALU + 2 shfl_xor (16,32)  [was 8 chained shfl
//     per row x 16 rows -> the serial LDS-latency chain that bounded attn]
//   - inv is lane-local -> P normalized in-reg, written as 16 ds_write_b64
//     (packed 4 consecutive k) directly in the PV-read swizzle layout.
// V global loads issued BEFORE Q/K gld_lds so the Vt transpose only waits
// on its own loads (vmcnt(8)), overlapping with Q/K staging.
// ---------------------------------------------------------------------------
__global__ __launch_bounds__(256) void attn_kernel4(
    bf16* __restrict__ qbuf, const bf16* __restrict__ kv,
    const float* __restrict__ bmr)
{
    __shared__ __attribute__((aligned(16))) bf16 smem[24576];  // 48 KB
    const int t    = threadIdx.x;
    const int wv   = t >> 6;                 // local head 0..3
    const int lane = t & 63;
    const int q    = lane >> 4;
    const int r16  = lane & 15;
    const int bw   = blockIdx.x >> 2;        // window 0..1023
    const int hg   = blockIdx.x & 3;         // head group
    const int h    = hg * 4 + wv;
    const int nw   = bw & 63;
    const long rowbase = (long)bw * 64;

    bf16* Qs = smem + wv * 6144;   // [64][32] chunk-swizzled
    bf16* Ks = Qs + 2048;          // [64][32]
    bf16* Vt = Qs + 4096;          // [32][64] chunk-swizzled (key=row&7)
    bf16* Ps = Qs;                 // [64][64] reuses Q+K after QK^T

    // V loads FIRST (retire before the 8 gld_lds -> transpose overlaps Q/K)
    const bf16* gv = kv + (rowbase + lane) * 1024 + 512 + h * 32;
    uint4 vtmp[4];
#pragma unroll
    for (int jj = 0; jj < 4; ++jj) vtmp[jj] = ((const uint4*)gv)[jj];

    // stage Q,K (own head): pre-swizzled global chunk source
    const int sc8 = (((lane & 3) ^ ((lane >> 4) & 3)) << 3);
#pragma unroll
    for (int it = 0; it < 4; ++it) {
        const int tok = it * 16 + (lane >> 2);
        gld_lds16(qbuf + (rowbase + tok) * 512  + h * 32 + sc8, Qs + it * 512);
        gld_lds16(kv   + (rowbase + tok) * 1024 + h * 32 + sc8, Ks + it * 512);
    }
    // Vt transpose (waits only on the 4 V loads; Q/K still in flight)
    {
        const bf16* vrow = (const bf16*)vtmp;
        const int tchunk = lane >> 3, tin = lane & 7;
#pragma unroll
        for (int hd = 0; hd < 32; ++hd)
            Vt[hd * 64 + ((tchunk ^ (hd & 7)) << 3) + tin] = vrow[hd];
    }
    asm volatile("s_waitcnt vmcnt(0)" ::: "memory");
    // no __syncthreads: each wave reads only its own head's region.

    const int cq8 = ((q ^ ((r16 >> 2) & 3)) << 3);
    f32x4 acc[4][4];   // acc[tk][tq]
    {
        bf16x8 kf[4], qf[4];
#pragma unroll
        for (int tk = 0; tk < 4; ++tk)
            kf[tk] = *(const bf16x8*)&Ks[(tk * 16 + r16) * 32 + cq8];
#pragma unroll
        for (int tq = 0; tq < 4; ++tq)
            qf[tq] = *(const bf16x8*)&Qs[(tq * 16 + r16) * 32 + cq8];
        const f32x4 z = f32x4{0.f, 0.f, 0.f, 0.f};
#pragma unroll
        for (int tk = 0; tk < 4; ++tk)
#pragma unroll
            for (int tq = 0; tq < 4; ++tq)
                acc[tk][tq] = __builtin_amdgcn_mfma_f32_16x16x32_bf16(
                    kf[tk], qf[tq], z, 0, 0, 0);
    }

    // softmax in log2-units, lane-local rows (scores already *log2e)
    const float* bmw = bmr + ((long)(nw * 16 + h) << 12);
#pragma unroll
    for (int tq = 0; tq < 4; ++tq) {
        f32x4 s[4];
#pragma unroll
        for (int tk = 0; tk < 4; ++tk)
            s[tk] = acc[tk][tq]
                  + *(const f32x4*)(bmw + ((tq * 4 + tk) * 64 + lane) * 4);
        float mx = -1e30f;
#pragma unroll
        for (int tk = 0; tk < 4; ++tk)
#pragma unroll
            for (int r = 0; r < 4; ++r) mx = fmaxf(mx, s[tk][r]);
        mx = fmaxf(mx, __shfl_xor(mx, 16));
        mx = fmaxf(mx, __shfl_xor(mx, 32));
        float sum = 0.f;
#pragma unroll
        for (int tk = 0; tk < 4; ++tk)
#pragma unroll
            for (int r = 0; r < 4; ++r) {
                float e = exp2f(s[tk][r] - mx);
                s[tk][r] = e;
                sum += e;
            }
        sum += __shfl_xor(sum, 16);
        sum += __shfl_xor(sum, 32);
        const float inv = 1.0f / sum;
        const int qrow = tq * 16 + r16;
#pragma unroll
        for (int tk = 0; tk < 4; ++tk) {
            bf16x4 pv;
#pragma unroll
            for (int r = 0; r < 4; ++r) pv[r] = (bf16)(s[tk][r] * inv);
            // k = tk*16 + q*4 + r -> chunk = tk*2 + (q>>1), sub = (q&1)*4
            *(bf16x4*)&Ps[qrow * 64 +
                          (((tk * 2 + (q >> 1)) ^ (qrow & 7)) << 3) +
                          (q & 1) * 4] = pv;
        }
    }

    f32x4 o[4][2];
#pragma unroll
    for (int ti = 0; ti < 4; ++ti)
#pragma unroll
        for (int tn = 0; tn < 2; ++tn)
            o[ti][tn] = f32x4{0.f, 0.f, 0.f, 0.f};

#pragma unroll
    for (int ks = 0; ks < 2; ++ks) {
        bf16x8 av[4], bv[2];
        const int ch = (((ks * 4 + q) ^ (r16 & 7)) << 3);
#pragma unroll
        for (int ti = 0; ti < 4; ++ti)
            av[ti] = *(const bf16x8*)&Ps[(ti * 16 + r16) * 64 + ch];
#pragma unroll
        for (int tn = 0; tn < 2; ++tn)
            bv[tn] = *(const bf16x8*)&Vt[(tn * 16 + r16) * 64 + ch];
#pragma unroll
        for (int ti = 0; ti < 4; ++ti)
#pragma unroll
            for (int tn = 0; tn < 2; ++tn)
                o[ti][tn] = __builtin_amdgcn_mfma_f32_16x16x32_bf16(
                    av[ti], bv[tn], o[ti][tn], 0, 0, 0);
    }

    // stage o into LDS (plain [64][32] at region base; P is dead now)
#pragma unroll
    for (int ti = 0; ti < 4; ++ti)
#pragma unroll
        for (int tn = 0; tn < 2; ++tn)
#pragma unroll
            for (int r = 0; r < 4; ++r)
                Qs[(ti * 16 + q * 4 + r) * 32 + tn * 16 + r16] =
                    (bf16)(o[ti][tn][r]);
    __syncthreads();

    // cooperative coalesced store: 64 rows x 128 cols (4 heads) bf16
    bf16* op = qbuf + rowbase * 512 + hg * 128;
#pragma unroll
    for (int it = 0; it < 4; ++it) {
        const int idx = it * 256 + t;            // 0..1023 16B-chunks
        const int row = idx >> 4;
        const int c   = idx & 15;
        const int hl  = c >> 2;
        uint4 v = *(const uint4*)(smem + hl * 6144 + row * 32 + (c & 3) * 8);
        *(uint4*)(op + (long)row * 512 + hl * 32 + (c & 3) * 8) = v;
    }
}

// ---------------------------------------------------------------------------
extern "C" void kernel_launch(void* const* d_in, const int* in_sizes, int n_in,
                              void* d_out, int out_size, void* d_ws, size_t ws_size,
                              hipStream_t stream) {
    const float* x      = (const float*)d_in[0];
    const float* mask   = (const float*)d_in[1];
    const float* qkv_w  = (const float*)d_in[2];
    const float* qkv_b  = (const float*)d_in[3];
    const float* table  = (const float*)d_in[4];
    const float* proj_w = (const float*)d_in[5];
    const float* proj_b = (const float*)d_in[6];
    const int*   relidx = (const int*)d_in[7];
    float* out = (float*)d_out;

    // ws layout (bytes):
    //   (spare) @ 0        256 KB
    //   qbuf  @ 262144     67.1 MB  bf16 q (pre-scaled), then attn-out in place
    //   xbf   @ 67371008   67.1 MB  bf16 x; REUSED as bmr (16.8 MB fp32) after gemm1
    //   wq    @ 134479872  1.57 MB  bf16 qkv_w
    //   wp    @ 136052736  0.52 MB  bf16 proj_w
    //   kv    @ 136577024  134.2 MB bf16 [k|v]  (or aliased to d_out if ws small)
    char*  ws   = (char*)d_ws;
    bf16*  qbuf = (bf16*)(ws + 262144);
    bf16*  xbf  = (bf16*)(ws + 67371008);
    float* bmr  = (float*)(ws + 67371008);   // aliases xbf (dead after gemm1)
    bf16*  wq   = (bf16*)(ws + 134479872);
    bf16*  wp   = (bf16*)(ws + 136052736);
    const size_t need_full = 136577024ull + 134217728ull;  // 270.8 MB
    bf16* kvbuf = (ws_size >= need_full) ? (bf16*)(ws + 136577024)
                                         : (bf16*)d_out;

    cvt_kernel<<<2048, 256, 0, stream>>>(x,      xbf, 8388608);  // 33.5M elems
    cvt_kernel<<<768,  256, 0, stream>>>(qkv_w,  wq,  196608);
    cvt_kernel<<<256,  256, 0, stream>>>(proj_w, wp,  65536);

    gemm1_qkv8<<<1536, 512, 0, stream>>>(xbf, wq, qkv_b, qbuf, kvbuf);
    bmr_kernel<<<16384, 256, 0, stream>>>(relidx, table, mask, bmr);
    attn_kernel4<<<4096, 256, 0, stream>>>(qbuf, kvbuf, bmr);
    gemm2_proj8<<<512, 512, 0, stream>>>(qbuf, wp, proj_b, out);
}